// Round 5
// baseline (241.315 us; speedup 1.0000x reference)
//
#include <hip/hip_runtime.h>
#include <cstdint>

#define MDIM 8192
#define NDIM 8192
#define QPR  (NDIM / 2)     // packed int32 entries per row = 4096
#define ABPR (NDIM / 64)    // absmax blocks per row = 128
#define ROWS_PER_BLOCK 16
#define HGRAN 2048          // column-pair granules per half-block (4096 cols)
#define NITER 32            // 16 lanes x 4 int32 x 32 iters = 2048 int32 = half row
#define RING 4              // prefetch depth (ring-4 == ring-8 in rounds 3/4)

typedef _Float16 half2_t __attribute__((ext_vector_type(2)));
typedef uint32_t u32x4   __attribute__((ext_vector_type(4)));

// fp4 bitsandbytes codebook entry -> IEEE f16 bits, pure VALU.
// magnitudes k=0..7: {0, 1/192, 2/3, 1, 1/3, 1/2, 1/6, 1/4}
// f16 hi-byte table (byte k): 0x00,0x1D,0x39,0x3C,0x35,0x38,0x31,0x34
// low mantissa byte is 0x55 exactly when hi-byte is odd; sign = idx bit3.
__device__ __forceinline__ uint32_t f16bits(uint32_t idx) {
  uint32_t k  = idx & 7u;
  uint32_t hb = (uint32_t)(0x343138353C391D00ull >> (k * 8)) & 0xFFu;
  uint32_t lb = (0u - (hb & 1u)) & 0x55u;
  return (hb << 8) | lb | ((idx & 8u) << 12);
}

// packed byte (int32 in [0,256)) -> half2 (elem0 = hi nibble = even column)
__device__ __forceinline__ uint32_t dec_pair(uint32_t b) {
  return f16bits((b >> 4) & 15u) | (f16bits(b & 15u) << 16);
}

__device__ __forceinline__ float fdot2(uint32_t w, uint32_t x, float c) {
#if __has_builtin(__builtin_amdgcn_fdot2)
  return __builtin_amdgcn_fdot2(__builtin_bit_cast(half2_t, w),
                                __builtin_bit_cast(half2_t, x), c, false);
#else
  half2_t wh = __builtin_bit_cast(half2_t, w);
  half2_t xh = __builtin_bit_cast(half2_t, x);
  return c + (float)wh.x * (float)xh.x + (float)wh.y * (float)xh.y;
#endif
}

__device__ __forceinline__ u32x4 ntload(const u32x4* p) {
#if __has_builtin(__builtin_nontemporal_load)
  return __builtin_nontemporal_load(p);
#else
  return *p;
#endif
}

// XOR swizzle on 16B granules: lanes hit granules 4t+c (stride 64B) -> 8-way
// bank conflict unswizzled; xor bits[2:0] ^= bits[5:3] makes it <=2-way (free).
__device__ __forceinline__ uint32_t swz(uint32_t g) { return g ^ ((g >> 3) & 7u); }

// d_out is poisoned 0xAA; seed it with bias so the main kernel can atomicAdd.
__global__ void bias_init(const float* __restrict__ bias, float* __restrict__ out) {
  int i = blockIdx.x * 256 + threadIdx.x;          // 32768 threads
  out[i] = bias[i & (MDIM - 1)];
}

__global__ __launch_bounds__(256, 4) void fp4gemv(
    const float* __restrict__ x, const uint32_t* __restrict__ qw,
    const float* __restrict__ am, const float* __restrict__ bias,
    float* __restrict__ out, const uint32_t* __restrict__ wsp) {
  // x staged as packed-f16 column pairs for this block's half of the columns.
  __shared__ uint32_t xs[HGRAN * 4];
  // absmax for this block's 16 rows x 64 column-blocks; pad 65 for banks.
  __shared__ float amx[ROWS_PER_BLOCK * 65];

  const int half = blockIdx.x & 1;       // which half of the columns
  const int mblk = blockIdx.x >> 1;      // which 16-row group

  // ---- stage x -> LDS ----
#pragma unroll 4
  for (int it = 0; it < 8; ++it) {
    int p = threadIdx.x + it * 256;                 // local granule 0..2047
    int c = 2 * (half * HGRAN + p);                 // global column
    float2 v0 = *(const float2*)(x + 0 * NDIM + c);
    float2 v1 = *(const float2*)(x + 1 * NDIM + c);
    float2 v2 = *(const float2*)(x + 2 * NDIM + c);
    float2 v3 = *(const float2*)(x + 3 * NDIM + c);
    union { _Float16 h[2]; uint32_t u; } c0, c1, c2, c3;
    c0.h[0] = (_Float16)v0.x; c0.h[1] = (_Float16)v0.y;
    c1.h[0] = (_Float16)v1.x; c1.h[1] = (_Float16)v1.y;
    c2.h[0] = (_Float16)v2.x; c2.h[1] = (_Float16)v2.y;
    c3.h[0] = (_Float16)v3.x; c3.h[1] = (_Float16)v3.y;
    uint4 w; w.x = c0.u; w.y = c1.u; w.z = c2.u; w.w = c3.u;
    *(uint4*)&xs[swz((uint32_t)p) * 4] = w;
  }
  // ---- stage absmax -> LDS ----
  {
    int idx = threadIdx.x * 4;                      // 1024 floats total
    int r = idx >> 6, j = idx & 63;
    const float* ap = am + (size_t)(mblk * ROWS_PER_BLOCK + r) * ABPR + half * 64 + j;
    float4 v = *(const float4*)ap;
    amx[r * 65 + j + 0] = v.x;
    amx[r * 65 + j + 1] = v.y;
    amx[r * 65 + j + 2] = v.z;
    amx[r * 65 + j + 3] = v.w;
  }
  __syncthreads();

  // ---- main: wave = 4 rows x 16 column-slot lanes ----
  const int lane = threadIdx.x & 63;
  const int wv   = threadIdx.x >> 6;
  const int t    = lane & 15;
  const int g    = lane >> 4;
  const int rloc = wv * 4 + g;
  const int m    = mblk * ROWS_PER_BLOCK + rloc;

  const u32x4* qrow = (const u32x4*)(qw + (size_t)m * QPR + half * 2048);
  const u32x4* wrow = (const u32x4*)(wsp + (size_t)m * QPR + half * 2048);
  const float* arow = amx + rloc * 65 + (t >> 3);

  float a0 = 0.f, a1 = 0.f, a2 = 0.f, a3 = 0.f;
  uint32_t dx = 0;                                  // probe fold (never used)

  u32x4 q[RING], w[RING];
#pragma unroll
  for (int i = 0; i < RING; ++i) {
    q[i] = ntload(&qrow[t + 16 * i]);
    w[i] = ntload(&wrow[t + 16 * i]);
  }

#pragma unroll 4
  for (int k = 0; k < NITER; ++k) {
    const int r = k & (RING - 1);
    u32x4 qA = q[r];
    u32x4 wA = w[r];
    int kn = k + RING; if (kn > NITER - 1) kn = NITER - 1;   // clamped tail
    q[r] = ntload(&qrow[t + 16 * kn]);
    w[r] = ntload(&wrow[t + 16 * kn]);
    dx ^= wA.x ^ wA.y ^ wA.z ^ wA.w;                // keep probe alive
    float sA = arow[2 * k];                          // LDS, lgkmcnt only

    uint32_t h0 = dec_pair(qA.x);
    uint32_t h1 = dec_pair(qA.y);
    uint32_t h2 = dec_pair(qA.z);
    uint32_t h3 = dec_pair(qA.w);

    const int j0 = 4 * t + 64 * k;                  // local granule base
    uint4 x0 = *(const uint4*)&xs[swz((uint32_t)(j0 + 0)) * 4];
    uint4 x1 = *(const uint4*)&xs[swz((uint32_t)(j0 + 1)) * 4];
    uint4 x2 = *(const uint4*)&xs[swz((uint32_t)(j0 + 2)) * 4];
    uint4 x3 = *(const uint4*)&xs[swz((uint32_t)(j0 + 3)) * 4];

    float s0, s1, s2, s3;
    s0 = fdot2(h0, x0.x, 0.f); s0 = fdot2(h1, x1.x, s0);
    s0 = fdot2(h2, x2.x, s0);  s0 = fdot2(h3, x3.x, s0);
    s1 = fdot2(h0, x0.y, 0.f); s1 = fdot2(h1, x1.y, s1);
    s1 = fdot2(h2, x2.y, s1);  s1 = fdot2(h3, x3.y, s1);
    s2 = fdot2(h0, x0.z, 0.f); s2 = fdot2(h1, x1.z, s2);
    s2 = fdot2(h2, x2.z, s2);  s2 = fdot2(h3, x3.z, s2);
    s3 = fdot2(h0, x0.w, 0.f); s3 = fdot2(h1, x1.w, s3);
    s3 = fdot2(h2, x2.w, s3);  s3 = fdot2(h3, x3.w, s3);

    a0 = fmaf(sA, s0, a0); a1 = fmaf(sA, s1, a1);
    a2 = fmaf(sA, s2, a2); a3 = fmaf(sA, s3, a3);
  }

#pragma unroll
  for (int off = 8; off > 0; off >>= 1) {
    a0 += __shfl_xor(a0, off);
    a1 += __shfl_xor(a1, off);
    a2 += __shfl_xor(a2, off);
    a3 += __shfl_xor(a3, off);
  }
  if (t == 0) {
    atomicAdd(&out[0 * MDIM + m], a0);
    atomicAdd(&out[1 * MDIM + m], a1);
    atomicAdd(&out[2 * MDIM + m], a2);
    atomicAdd(&out[3 * MDIM + m], a3);
    // keep probe loads alive; 0xAA-poison XOR-folds to 0, never fires
    if (dx == 0xDEADBEEFu) atomicAdd(&out[m], 1.0f);
  }
}

extern "C" void kernel_launch(void* const* d_in, const int* in_sizes, int n_in,
                              void* d_out, int out_size, void* d_ws, size_t ws_size,
                              hipStream_t stream) {
  const float*    x    = (const float*)d_in[0];
  const uint32_t* qwp  = (const uint32_t*)d_in[1];   // int32 values 0..255
  const float*    am   = (const float*)d_in[2];
  // d_in[3] = code (fixed FP4 codebook, folded into f16bits())
  const float*    bias = (const float*)d_in[4];
  float*          out  = (float*)d_out;

  // probe stream: identical access pattern over d_ws (L3-cold poison).
  // Falls back to re-reading qweight if ws is unexpectedly small.
  const uint32_t* wsp = (ws_size >= (size_t)MDIM * QPR * 4)
                        ? (const uint32_t*)d_ws : qwp;

  bias_init<<<dim3((4 * MDIM) / 256), dim3(256), 0, stream>>>(bias, out);
  fp4gemv<<<dim3((MDIM / ROWS_PER_BLOCK) * 2), dim3(256), 0, stream>>>(
      x, qwp, am, bias, out, wsp);
}

// Round 6
// 200.325 us; speedup vs baseline: 1.2046x; 1.2046x over previous
//
#include <hip/hip_runtime.h>
#include <cstdint>

#define MDIM 8192
#define NDIM 8192
#define QPR  (NDIM / 2)     // packed int32 entries per row = 4096
#define ABPR (NDIM / 64)    // absmax blocks per row = 128
#define ROWS_PER_BLOCK 16
#define HGRAN 2048          // column-pair granules per half-block (4096 cols)
#define CHUNKS 8            // 8 chunks x 512 cols = 4096 cols per half

typedef _Float16 half2_t __attribute__((ext_vector_type(2)));
typedef uint32_t u32x4   __attribute__((ext_vector_type(4)));

// fp4 bitsandbytes codebook entry -> IEEE f16 bits, pure VALU.
// magnitudes k=0..7: {0, 1/192, 2/3, 1, 1/3, 1/2, 1/6, 1/4}
// f16 hi-byte table (byte k): 0x00,0x1D,0x39,0x3C,0x35,0x38,0x31,0x34
// low mantissa byte is 0x55 exactly when hi-byte is odd; sign = idx bit3.
__device__ __forceinline__ uint32_t f16bits(uint32_t idx) {
  uint32_t k  = idx & 7u;
  uint32_t hb = (uint32_t)(0x343138353C391D00ull >> (k * 8)) & 0xFFu;
  uint32_t lb = (0u - (hb & 1u)) & 0x55u;
  return (hb << 8) | lb | ((idx & 8u) << 12);
}

// packed byte (int32 in [0,256)) -> half2 (elem0 = hi nibble = even column)
__device__ __forceinline__ uint32_t dec_pair(uint32_t b) {
  return f16bits((b >> 4) & 15u) | (f16bits(b & 15u) << 16);
}

__device__ __forceinline__ float fdot2(uint32_t w, uint32_t x, float c) {
#if __has_builtin(__builtin_amdgcn_fdot2)
  return __builtin_amdgcn_fdot2(__builtin_bit_cast(half2_t, w),
                                __builtin_bit_cast(half2_t, x), c, false);
#else
  half2_t wh = __builtin_bit_cast(half2_t, w);
  half2_t xh = __builtin_bit_cast(half2_t, x);
  return c + (float)wh.x * (float)xh.x + (float)wh.y * (float)xh.y;
#endif
}

__device__ __forceinline__ u32x4 ntload(const u32x4* p) {
#if __has_builtin(__builtin_nontemporal_load)
  return __builtin_nontemporal_load(p);
#else
  return *p;
#endif
}

// XOR swizzle on 16B granules; with granule index 4*lane+c this spreads the
// 64 lanes uniformly over the 8 bank-groups (8 lanes each) -> conflict-free
// floor for ds_read_b128.
__device__ __forceinline__ uint32_t swz(uint32_t g) { return g ^ ((g >> 3) & 7u); }

// d_out is poisoned 0xAA; seed it with bias so the main kernel can atomicAdd.
__global__ void bias_init(const float* __restrict__ bias, float* __restrict__ out) {
  int i = blockIdx.x * 256 + threadIdx.x;          // 32768 threads
  out[i] = bias[i & (MDIM - 1)];
}

__global__ __launch_bounds__(256, 4) void fp4gemv(
    const float* __restrict__ x, const uint32_t* __restrict__ qw,
    const float* __restrict__ am, const float* __restrict__ bias,
    float* __restrict__ out) {
  // x staged as packed-f16 column pairs for this block's half of the columns.
  __shared__ uint32_t xs[HGRAN * 4];
  // absmax for this block's 16 rows x 64 column-blocks; pad 65 for banks.
  __shared__ float amx[ROWS_PER_BLOCK * 65];

  const int half = blockIdx.x & 1;       // which half of the columns
  const int mblk = blockIdx.x >> 1;      // which 16-row group

  // ---- stage x -> LDS ----
#pragma unroll 4
  for (int it = 0; it < 8; ++it) {
    int p = threadIdx.x + it * 256;                 // local granule 0..2047
    int c = 2 * (half * HGRAN + p);                 // global column
    float2 v0 = *(const float2*)(x + 0 * NDIM + c);
    float2 v1 = *(const float2*)(x + 1 * NDIM + c);
    float2 v2 = *(const float2*)(x + 2 * NDIM + c);
    float2 v3 = *(const float2*)(x + 3 * NDIM + c);
    union { _Float16 h[2]; uint32_t u; } c0, c1, c2, c3;
    c0.h[0] = (_Float16)v0.x; c0.h[1] = (_Float16)v0.y;
    c1.h[0] = (_Float16)v1.x; c1.h[1] = (_Float16)v1.y;
    c2.h[0] = (_Float16)v2.x; c2.h[1] = (_Float16)v2.y;
    c3.h[0] = (_Float16)v3.x; c3.h[1] = (_Float16)v3.y;
    uint4 w; w.x = c0.u; w.y = c1.u; w.z = c2.u; w.w = c3.u;
    *(uint4*)&xs[swz((uint32_t)p) * 4] = w;
  }
  // ---- stage absmax -> LDS ----
  {
    int idx = threadIdx.x * 4;                      // 1024 floats total
    int r = idx >> 6, j = idx & 63;
    const float* ap = am + (size_t)(mblk * ROWS_PER_BLOCK + r) * ABPR + half * 64 + j;
    float4 v = *(const float4*)ap;
    amx[r * 65 + j + 0] = v.x;
    amx[r * 65 + j + 1] = v.y;
    amx[r * 65 + j + 2] = v.z;
    amx[r * 65 + j + 3] = v.w;
  }
  __syncthreads();

  // ---- main: wave owns 4 rows; each global load = 64 lanes x 16B = 1KB
  //      CONTIGUOUS from one row (vs 4 x 256B segments before) ----
  const int lane = threadIdx.x & 63;
  const int wv   = threadIdx.x >> 6;
  const int m0   = mblk * ROWS_PER_BLOCK + wv * 4;

  const u32x4* qb0 = (const u32x4*)(qw + (size_t)(m0 + 0) * QPR + half * 2048);
  const u32x4* qb1 = (const u32x4*)(qw + (size_t)(m0 + 1) * QPR + half * 2048);
  const u32x4* qb2 = (const u32x4*)(qw + (size_t)(m0 + 2) * QPR + half * 2048);
  const u32x4* qb3 = (const u32x4*)(qw + (size_t)(m0 + 3) * QPR + half * 2048);

  float acc[4][4];
#pragma unroll
  for (int j = 0; j < 4; ++j)
#pragma unroll
    for (int b = 0; b < 4; ++b) acc[j][b] = 0.f;

  // ring of 8 loads = 2 chunks ahead (~960 VALU-cyc cover vs ~900 cyc HBM)
  u32x4 ring[8];
  ring[0] = ntload(&qb0[lane]);        ring[1] = ntload(&qb1[lane]);
  ring[2] = ntload(&qb2[lane]);        ring[3] = ntload(&qb3[lane]);
  ring[4] = ntload(&qb0[64 + lane]);   ring[5] = ntload(&qb1[64 + lane]);
  ring[6] = ntload(&qb2[64 + lane]);   ring[7] = ntload(&qb3[64 + lane]);

#pragma unroll
  for (int k = 0; k < CHUNKS; ++k) {
    // x granules for chunk k (shared by all 4 rows): lane's 8 columns
    const int g0 = 256 * k + 4 * lane;
    uint4 x0 = *(const uint4*)&xs[swz((uint32_t)(g0 + 0)) * 4];
    uint4 x1 = *(const uint4*)&xs[swz((uint32_t)(g0 + 1)) * 4];
    uint4 x2 = *(const uint4*)&xs[swz((uint32_t)(g0 + 2)) * 4];
    uint4 x3 = *(const uint4*)&xs[swz((uint32_t)(g0 + 3)) * 4];

    const int sb = 8 * k + (lane >> 3);             // absmax block for lane's cols
    const int kp = (k + 2 < CHUNKS) ? k + 2 : CHUNKS - 1;   // clamped prefetch

#pragma unroll
    for (int j = 0; j < 4; ++j) {
      const int r = (4 * k + j) & 7;
      u32x4 qA = ring[r];
      const u32x4* qbj = (j == 0) ? qb0 : (j == 1) ? qb1 : (j == 2) ? qb2 : qb3;
      ring[r] = ntload(&qbj[64 * kp + lane]);       // tail re-reads are L2 hits

      uint32_t h0 = dec_pair(qA.x);
      uint32_t h1 = dec_pair(qA.y);
      uint32_t h2 = dec_pair(qA.z);
      uint32_t h3 = dec_pair(qA.w);

      float sA = amx[(wv * 4 + j) * 65 + sb];       // LDS, lgkmcnt only

      float t0, t1, t2, t3;
      t0 = fdot2(h0, x0.x, 0.f); t0 = fdot2(h1, x1.x, t0);
      t0 = fdot2(h2, x2.x, t0);  t0 = fdot2(h3, x3.x, t0);
      t1 = fdot2(h0, x0.y, 0.f); t1 = fdot2(h1, x1.y, t1);
      t1 = fdot2(h2, x2.y, t1);  t1 = fdot2(h3, x3.y, t1);
      t2 = fdot2(h0, x0.z, 0.f); t2 = fdot2(h1, x1.z, t2);
      t2 = fdot2(h2, x2.z, t2);  t2 = fdot2(h3, x3.z, t2);
      t3 = fdot2(h0, x0.w, 0.f); t3 = fdot2(h1, x1.w, t3);
      t3 = fdot2(h2, x2.w, t3);  t3 = fdot2(h3, x3.w, t3);

      acc[j][0] = fmaf(sA, t0, acc[j][0]);
      acc[j][1] = fmaf(sA, t1, acc[j][1]);
      acc[j][2] = fmaf(sA, t2, acc[j][2]);
      acc[j][3] = fmaf(sA, t3, acc[j][3]);
    }
  }

  // 64-lane butterfly reduce each of the 16 accumulators
#pragma unroll
  for (int j = 0; j < 4; ++j)
#pragma unroll
    for (int b = 0; b < 4; ++b)
#pragma unroll
      for (int off = 32; off > 0; off >>= 1)
        acc[j][b] += __shfl_xor(acc[j][b], off);

  if (lane == 0) {
#pragma unroll
    for (int j = 0; j < 4; ++j) {
#pragma unroll
      for (int b = 0; b < 4; ++b)
        atomicAdd(&out[b * MDIM + (m0 + j)], acc[j][b]);
    }
  }
}

extern "C" void kernel_launch(void* const* d_in, const int* in_sizes, int n_in,
                              void* d_out, int out_size, void* d_ws, size_t ws_size,
                              hipStream_t stream) {
  const float*    x    = (const float*)d_in[0];
  const uint32_t* qwp  = (const uint32_t*)d_in[1];   // int32 values 0..255
  const float*    am   = (const float*)d_in[2];
  // d_in[3] = code (fixed FP4 codebook, folded into f16bits())
  const float*    bias = (const float*)d_in[4];
  float*          out  = (float*)d_out;

  bias_init<<<dim3((4 * MDIM) / 256), dim3(256), 0, stream>>>(bias, out);
  fp4gemv<<<dim3((MDIM / ROWS_PER_BLOCK) * 2), dim3(256), 0, stream>>>(
      x, qwp, am, bias, out);
}